// Round 2
// baseline (588.886 us; speedup 1.0000x reference)
//
#include <hip/hip_runtime.h>
#include <hip/hip_bf16.h>
#include <stdint.h>

#define EPS 1e-5f

typedef int v4i __attribute__((ext_vector_type(4)));
typedef int v16i __attribute__((ext_vector_type(16)));
typedef const __attribute__((address_space(1))) void g_void;
typedef __attribute__((address_space(3))) void l_void;

// ---------------- block reductions ----------------
__device__ inline float block_max_nw(float v, int nw) {
    __shared__ float s[8];
#pragma unroll
    for (int o = 32; o; o >>= 1) v = fmaxf(v, __shfl_xor(v, o, 64));
    if ((threadIdx.x & 63) == 0) s[threadIdx.x >> 6] = v;
    __syncthreads();
    float m = s[0];
    for (int i = 1; i < nw; ++i) m = fmaxf(m, s[i]);
    return m;
}

__device__ inline float block_sum64x4(float v) {
    __shared__ float s[4];
#pragma unroll
    for (int o = 32; o; o >>= 1) v += __shfl_xor(v, o, 64);
    if ((threadIdx.x & 63) == 0) s[threadIdx.x >> 6] = v;
    __syncthreads();
    return s[0] + s[1] + s[2] + s[3];
}

// ---------------- |w| sum: stage 1 (deterministic partials, fixed grid 1024) ----
__global__ __launch_bounds__(256) void abs_sum_part_k(const float4* __restrict__ w,
                                                      int n4, float* __restrict__ part) {
    float s = 0.0f;
    for (int i = blockIdx.x * 256 + threadIdx.x; i < n4; i += 1024 * 256) {
        float4 v = w[i];
        s += fabsf(v.x) + fabsf(v.y) + fabsf(v.z) + fabsf(v.w);
    }
    s = block_sum64x4(s);
    if (threadIdx.x == 0) part[blockIdx.x] = s;
}

// ---------------- |w| sum: stage 2 ----------
__global__ __launch_bounds__(256) void abs_sum_final_k(const float* __restrict__ parts,
                                                       float* __restrict__ sums) {
    const float* p = parts + blockIdx.x * 1024;
    const int t = threadIdx.x;
    float s = p[t] + p[t + 256] + p[t + 512] + p[t + 768];
    s = block_sum64x4(s);
    if (t == 0) sums[blockIdx.x] = s;
}

// ---------------- ternary weight quantization ----------------
__global__ __launch_bounds__(256) void wquant_k(const float4* __restrict__ w,
                                                char4* __restrict__ q,
                                                const float* __restrict__ sum) {
    const float mean = fmaxf(sum[0] * (1.0f / 3145728.0f), EPS);
    const float scale = 1.0f / mean;
    const int i = blockIdx.x * 256 + threadIdx.x;
    float4 v = w[i];
    char4 c;
    c.x = (signed char)(int)fmaxf(fminf(rintf(v.x * scale), 1.0f), -1.0f);
    c.y = (signed char)(int)fmaxf(fminf(rintf(v.y * scale), 1.0f), -1.0f);
    c.z = (signed char)(int)fmaxf(fminf(rintf(v.z * scale), 1.0f), -1.0f);
    c.w = (signed char)(int)fmaxf(fminf(rintf(v.w * scale), 1.0f), -1.0f);
    q[i] = c;
}

// ---------------- per-token int8 quantization of x (rows of 1024 fp32) ----------
__global__ __launch_bounds__(256) void aquant_k(const float4* __restrict__ x,
                                                char4* __restrict__ q,
                                                float* __restrict__ deq) {
    const int row = blockIdx.x, t = threadIdx.x;
    const float4 v = x[(size_t)row * 256 + t];
    float m = fmaxf(fmaxf(fabsf(v.x), fabsf(v.y)), fmaxf(fabsf(v.z), fabsf(v.w)));
    m = block_max_nw(m, 4);
    const float mc = fmaxf(m, EPS);
    const float sc = 127.0f / mc;
    char4 c;
    c.x = (signed char)(int)fmaxf(fminf(rintf(v.x * sc), 127.0f), -128.0f);
    c.y = (signed char)(int)fmaxf(fminf(rintf(v.y * sc), 127.0f), -128.0f);
    c.z = (signed char)(int)fmaxf(fminf(rintf(v.z * sc), 127.0f), -128.0f);
    c.w = (signed char)(int)fmaxf(fminf(rintf(v.w * sc), 127.0f), -128.0f);
    q[(size_t)row * 256 + t] = c;
    if (t == 0) deq[row] = mc / 127.0f;
}

// ---------------- per-token quant of bf16 hidden rows (3072), IN PLACE ----------
__global__ __launch_bounds__(384) void hquant_k(unsigned short* __restrict__ hid,
                                                float* __restrict__ deq) {
    const size_t row = blockIdx.x;
    const int t = threadIdx.x;
    unsigned short* rp = hid + row * 3072;
    const uint4 u = ((const uint4*)rp)[t];
    float v[8];
    {
        uint32_t uu[4] = {u.x, u.y, u.z, u.w};
#pragma unroll
        for (int i = 0; i < 4; ++i) {
            uint32_t lo = uu[i] << 16, hi = uu[i] & 0xFFFF0000u;
            v[2 * i]     = __uint_as_float(lo);
            v[2 * i + 1] = __uint_as_float(hi);
        }
    }
    float m = 0.0f;
#pragma unroll
    for (int i = 0; i < 8; ++i) m = fmaxf(m, fabsf(v[i]));
    m = block_max_nw(m, 6);   // contains __syncthreads(): loads done before stores
    const float mc = fmaxf(m, EPS);
    const float sc = 127.0f / mc;
    uint32_t p0 = 0, p1 = 0;
#pragma unroll
    for (int i = 0; i < 4; ++i) {
        int c = (int)fminf(rintf(v[i] * sc), 127.0f);          // v >= 0 (relu^2)
        p0 |= (uint32_t)(c & 255) << (8 * i);
    }
#pragma unroll
    for (int i = 0; i < 4; ++i) {
        int c = (int)fminf(rintf(v[4 + i] * sc), 127.0f);
        p1 |= (uint32_t)(c & 255) << (8 * i);
    }
    uint2 pk; pk.x = p0; pk.y = p1;
    ((uint2*)rp)[t] = pk;
    if (t == 0) deq[row] = mc / 127.0f;
}

// ---------------- int8 GEMM: C[m][n] = sum_k A[m][k]*B[n][k] ----------------
// 256x256 tile, BK=64, 512 threads = 8 waves (2M x 4N), wave tile 128x64 as
// 4x2 tiles of v_mfma_i32_32x32x32_i8, 2 k-steps per tile.
// RING-4 LDS pipeline (128 KB): stage tile tt+3 at top of tile tt; ONE raw
// s_barrier per tile; counted vmcnt(8) (never 0 mid-loop). NO manual lgkmcnt:
// compiler's dependency waits retire each wave's ds_reads before its MFMAs,
// which precede the barrier, so re-staging a buffer one tile after its last
// read is race-free by construction. Stage->first-read distance = 3 tiles.
// LDS rows 64 B; 16 B chunks XOR-swizzled by (row>>1)&3, folded into the
// staging lanes' GLOBAL addresses (per-lane constant (l&3)^((l>>3)&3)).
// XCD-aware map: xcd = blk&7.
template <bool RELU2, typename OutT>
__global__ __launch_bounds__(512, 2) void gemm_i8(
    const int8_t* __restrict__ A, int lda,        // row pitch in bytes
    const int8_t* __restrict__ B, int ldb,
    OutT* __restrict__ O, int ldo,                // pitch in elements
    const float* __restrict__ rowDeq,
    const float* __restrict__ sumPtr,
    const float* __restrict__ bias,
    int K, int nTiles) {
    __shared__ __align__(16) char As[4][16384];   // 64 KB ring (256 rows x 64 B)
    __shared__ __align__(16) char Bs[4][16384];   // 64 KB ring
    const int t = threadIdx.x;
    const int lane = t & 63;
    const int w = t >> 6;                         // wave 0..7
    const int wm = w >> 2;                        // 0..1
    const int wn = w & 3;                         // 0..3
    const int xcd = blockIdx.x & 7;
    const int sb = blockIdx.x >> 3;
    const int bm = xcd + 8 * (sb / nTiles);
    const int bn = sb % nTiles;
    const long m0 = (long)bm * 256;
    const long n0 = (long)bn * 256;

    v16i acc[4][2];
#pragma unroll
    for (int i = 0; i < 4; ++i)
#pragma unroll
        for (int j = 0; j < 2; ++j) acc[i][j] = (v16i)(0);

    const int r32 = lane & 31;
    const int h = lane >> 5;

    // ---- staging geometry: 2 instrs/matrix/wave, 16 rows x 64 B each ----
    const int srow = lane >> 2;                   // 0..15 within 16-row group
    const int sc = ((lane & 3) ^ ((lane >> 3) & 3)) * 16;  // pre-swizzled chunk
    const int8_t* pa  = A + (m0 + 32 * w + srow) * (long)lda + sc;
    const int8_t* pb  = B + (n0 + 32 * w + srow) * (long)ldb + sc;
    const int8_t* pa1 = pa + 16 * (long)lda;
    const int8_t* pb1 = pb + 16 * (long)ldb;
    const int sdst = w * 2048;                    // wave's 2 KB LDS slice

    // ---- fragment-read geometry ----
    int cro[2];                                   // swizzled chunk byte per ks
#pragma unroll
    for (int ks = 0; ks < 2; ++ks) cro[ks] = ((2 * ks + h) ^ ((r32 >> 1) & 3)) * 16;
    const int arow = (wm * 128 + r32) * 64;       // + mt*2048
    const int brow = (wn * 64 + r32) * 64;        // + nt*2048

    const int NT = K >> 6;                        // K-tiles of 64 (NT >= 4 here)

    auto STAGE = [&](int tt) {                    // 4 global_load_lds per thread
        const int buf = tt & 3;
        const long ko = (long)tt << 6;
        __builtin_amdgcn_global_load_lds((g_void*)(pa + ko),
                                         (l_void*)(As[buf] + sdst), 16, 0, 0);
        __builtin_amdgcn_global_load_lds((g_void*)(pa1 + ko),
                                         (l_void*)(As[buf] + sdst + 1024), 16, 0, 0);
        __builtin_amdgcn_global_load_lds((g_void*)(pb + ko),
                                         (l_void*)(Bs[buf] + sdst), 16, 0, 0);
        __builtin_amdgcn_global_load_lds((g_void*)(pb1 + ko),
                                         (l_void*)(Bs[buf] + sdst + 1024), 16, 0, 0);
    };

    // prologue: tiles 0,1,2 in flight (12 loads); wait tile 0 only
    STAGE(0);
    STAGE(1);
    STAGE(2);
    asm volatile("s_waitcnt vmcnt(8)" ::: "memory");
    __builtin_amdgcn_s_barrier();
    __builtin_amdgcn_sched_barrier(0);

    for (int tt = 0; tt < NT; ++tt) {
        const char* ab = As[tt & 3];
        const char* bb = Bs[tt & 3];
        if (tt + 3 < NT) STAGE(tt + 3);           // -> buf (tt-1)&3, read last tile

        v4i af[4][2], bf[2][2];
#pragma unroll
        for (int mt = 0; mt < 4; ++mt)
#pragma unroll
            for (int ks = 0; ks < 2; ++ks)
                af[mt][ks] = *(const v4i*)(ab + arow + mt * 2048 + cro[ks]);
#pragma unroll
        for (int nt = 0; nt < 2; ++nt)
#pragma unroll
            for (int ks = 0; ks < 2; ++ks)
                bf[nt][ks] = *(const v4i*)(bb + brow + nt * 2048 + cro[ks]);

        __builtin_amdgcn_s_setprio(1);
#pragma unroll
        for (int ks = 0; ks < 2; ++ks)
#pragma unroll
            for (int mt = 0; mt < 4; ++mt)
#pragma unroll
                for (int nt = 0; nt < 2; ++nt)
                    acc[mt][nt] = __builtin_amdgcn_mfma_i32_32x32x32_i8(
                        af[mt][ks], bf[nt][ks], acc[mt][nt], 0, 0, 0);
        __builtin_amdgcn_s_setprio(0);

        // tile tt+1 must be landed; tiles tt+2/tt+3 stay in flight
        if (tt + 3 < NT)      asm volatile("s_waitcnt vmcnt(8)" ::: "memory");
        else if (tt + 2 < NT) asm volatile("s_waitcnt vmcnt(4)" ::: "memory");
        else                  asm volatile("s_waitcnt vmcnt(0)" ::: "memory");
        __builtin_amdgcn_s_barrier();
        __builtin_amdgcn_sched_barrier(0);
    }

    // epilogue: C/D layout col = lane&31, row = (reg&3) + 8*(reg>>2) + 4*(lane>>5)
    const float wdeq = fmaxf(sumPtr[0] * (1.0f / 3145728.0f), EPS);
#pragma unroll
    for (int mt = 0; mt < 4; ++mt) {
#pragma unroll
        for (int g = 0; g < 4; ++g) {
#pragma unroll
            for (int rr = 0; rr < 4; ++rr) {
                const long row = m0 + wm * 128 + mt * 32 + g * 8 + h * 4 + rr;
                const float rs = rowDeq[row] * wdeq;
#pragma unroll
                for (int nt = 0; nt < 2; ++nt) {
                    const long col = n0 + wn * 64 + nt * 32 + r32;
                    float val = (float)acc[mt][nt][g * 4 + rr] * rs + bias[col];
                    if (RELU2) {
                        val = fmaxf(val, 0.0f);
                        val = val * val;
                    }
                    O[row * (long)ldo + col] = (OutT)val;
                }
            }
        }
    }
}

// ---------------- launch ----------------
extern "C" void kernel_launch(void* const* d_in, const int* in_sizes, int n_in,
                              void* d_out, int out_size, void* d_ws, size_t ws_size,
                              hipStream_t stream) {
    const float* x      = (const float*)d_in[0];   // [32768,1024]
    const float* up_w   = (const float*)d_in[1];   // [3072,1024]
    const float* up_b   = (const float*)d_in[2];   // [3072]
    const float* down_w = (const float*)d_in[3];   // [1024,3072]
    const float* down_b = (const float*)d_in[4];   // [1024]

    // ws: sums 256B | parts 8KB | qw_dn 3MB | deqh 128KB | hidden bf16 201MB
    char* ws = (char*)d_ws;
    float*  sums   = (float*)ws;
    float*  parts  = (float*)(ws + 256);
    int8_t* qw_dn  = (int8_t*)(ws + 256 + 8192);
    float*  deqh   = (float*)(ws + 256 + 8192 + 3145728);
    __hip_bfloat16* hidden = (__hip_bfloat16*)(ws + 256 + 8192 + 3145728 + 131072);

    // d_out head as phase-1 scratch (dead before GEMM2 writes)
    int8_t* qx    = (int8_t*)d_out;                      // 33.5MB
    int8_t* qw_up = qx + 33554432;                       // 3MB
    float*  deqx  = (float*)(qx + 33554432 + 3145728);   // 128KB

    abs_sum_part_k<<<1024, 256, 0, stream>>>((const float4*)up_w, 786432, parts);
    abs_sum_part_k<<<1024, 256, 0, stream>>>((const float4*)down_w, 786432, parts + 1024);
    abs_sum_final_k<<<2, 256, 0, stream>>>(parts, sums);

    wquant_k<<<3072, 256, 0, stream>>>((const float4*)up_w, (char4*)qw_up, &sums[0]);
    wquant_k<<<3072, 256, 0, stream>>>((const float4*)down_w, (char4*)qw_dn, &sums[1]);
    aquant_k<<<32768, 256, 0, stream>>>((const float4*)x, (char4*)qx, deqx);

    // GEMM1: [32768,1024] x [3072,1024]^T -> hidden bf16 (relu^2 fused)
    // grid: 128 m-tiles x 12 n-tiles = 1536 blocks (divisible by 8 XCDs)
    gemm_i8<true, __hip_bfloat16><<<1536, 512, 0, stream>>>(
        qx, 1024, qw_up, 1024, hidden, 3072, deqx, &sums[0], up_b, 1024, 12);
    // quantize hidden rows in place (int8 overlaid, pitch 6144 B)
    hquant_k<<<32768, 384, 0, stream>>>((unsigned short*)hidden, deqh);
    // GEMM2: [32768,3072] x [1024,3072]^T -> d_out fp32
    // grid: 128 m-tiles x 4 n-tiles = 512 blocks
    gemm_i8<false, float><<<512, 512, 0, stream>>>(
        (const int8_t*)hidden, 6144, qw_dn, 3072, (float*)d_out, 1024,
        deqh, &sums[1], down_b, 3072, 4);
}

// Round 3
// 557.882 us; speedup vs baseline: 1.0556x; 1.0556x over previous
//
#include <hip/hip_runtime.h>
#include <hip/hip_bf16.h>
#include <stdint.h>

#define EPS 1e-5f

typedef int v4i __attribute__((ext_vector_type(4)));
typedef int v16i __attribute__((ext_vector_type(16)));
typedef const __attribute__((address_space(1))) void g_void;
typedef __attribute__((address_space(3))) void l_void;

// ---------------- block reductions ----------------
__device__ inline float block_max_nw(float v, int nw) {
    __shared__ float s[8];
#pragma unroll
    for (int o = 32; o; o >>= 1) v = fmaxf(v, __shfl_xor(v, o, 64));
    if ((threadIdx.x & 63) == 0) s[threadIdx.x >> 6] = v;
    __syncthreads();
    float m = s[0];
    for (int i = 1; i < nw; ++i) m = fmaxf(m, s[i]);
    return m;
}

__device__ inline float block_sum64x4(float v) {
    __shared__ float s[4];
#pragma unroll
    for (int o = 32; o; o >>= 1) v += __shfl_xor(v, o, 64);
    if ((threadIdx.x & 63) == 0) s[threadIdx.x >> 6] = v;
    __syncthreads();
    return s[0] + s[1] + s[2] + s[3];
}

// ---------------- |w| sum: stage 1 (deterministic partials, fixed grid 1024) ----
__global__ __launch_bounds__(256) void abs_sum_part_k(const float4* __restrict__ w,
                                                      int n4, float* __restrict__ part) {
    float s = 0.0f;
    for (int i = blockIdx.x * 256 + threadIdx.x; i < n4; i += 1024 * 256) {
        float4 v = w[i];
        s += fabsf(v.x) + fabsf(v.y) + fabsf(v.z) + fabsf(v.w);
    }
    s = block_sum64x4(s);
    if (threadIdx.x == 0) part[blockIdx.x] = s;
}

// ---------------- |w| sum: stage 2 ----------
__global__ __launch_bounds__(256) void abs_sum_final_k(const float* __restrict__ parts,
                                                       float* __restrict__ sums) {
    const float* p = parts + blockIdx.x * 1024;
    const int t = threadIdx.x;
    float s = p[t] + p[t + 256] + p[t + 512] + p[t + 768];
    s = block_sum64x4(s);
    if (t == 0) sums[blockIdx.x] = s;
}

// ---------------- ternary weight quantization ----------------
__global__ __launch_bounds__(256) void wquant_k(const float4* __restrict__ w,
                                                char4* __restrict__ q,
                                                const float* __restrict__ sum) {
    const float mean = fmaxf(sum[0] * (1.0f / 3145728.0f), EPS);
    const float scale = 1.0f / mean;
    const int i = blockIdx.x * 256 + threadIdx.x;
    float4 v = w[i];
    char4 c;
    c.x = (signed char)(int)fmaxf(fminf(rintf(v.x * scale), 1.0f), -1.0f);
    c.y = (signed char)(int)fmaxf(fminf(rintf(v.y * scale), 1.0f), -1.0f);
    c.z = (signed char)(int)fmaxf(fminf(rintf(v.z * scale), 1.0f), -1.0f);
    c.w = (signed char)(int)fmaxf(fminf(rintf(v.w * scale), 1.0f), -1.0f);
    q[i] = c;
}

// ---------------- per-token int8 quantization of x (rows of 1024 fp32) ----------
__global__ __launch_bounds__(256) void aquant_k(const float4* __restrict__ x,
                                                char4* __restrict__ q,
                                                float* __restrict__ deq) {
    const int row = blockIdx.x, t = threadIdx.x;
    const float4 v = x[(size_t)row * 256 + t];
    float m = fmaxf(fmaxf(fabsf(v.x), fabsf(v.y)), fmaxf(fabsf(v.z), fabsf(v.w)));
    m = block_max_nw(m, 4);
    const float mc = fmaxf(m, EPS);
    const float sc = 127.0f / mc;
    char4 c;
    c.x = (signed char)(int)fmaxf(fminf(rintf(v.x * sc), 127.0f), -128.0f);
    c.y = (signed char)(int)fmaxf(fminf(rintf(v.y * sc), 127.0f), -128.0f);
    c.z = (signed char)(int)fmaxf(fminf(rintf(v.z * sc), 127.0f), -128.0f);
    c.w = (signed char)(int)fmaxf(fminf(rintf(v.w * sc), 127.0f), -128.0f);
    q[(size_t)row * 256 + t] = c;
    if (t == 0) deq[row] = mc / 127.0f;
}

// ---------------- per-token quant of bf16 hidden rows (3072), IN PLACE ----------
__global__ __launch_bounds__(384) void hquant_k(unsigned short* __restrict__ hid,
                                                float* __restrict__ deq) {
    const size_t row = blockIdx.x;
    const int t = threadIdx.x;
    unsigned short* rp = hid + row * 3072;
    const uint4 u = ((const uint4*)rp)[t];
    float v[8];
    {
        uint32_t uu[4] = {u.x, u.y, u.z, u.w};
#pragma unroll
        for (int i = 0; i < 4; ++i) {
            uint32_t lo = uu[i] << 16, hi = uu[i] & 0xFFFF0000u;
            v[2 * i]     = __uint_as_float(lo);
            v[2 * i + 1] = __uint_as_float(hi);
        }
    }
    float m = 0.0f;
#pragma unroll
    for (int i = 0; i < 8; ++i) m = fmaxf(m, fabsf(v[i]));
    m = block_max_nw(m, 6);   // contains __syncthreads(): loads done before stores
    const float mc = fmaxf(m, EPS);
    const float sc = 127.0f / mc;
    uint32_t p0 = 0, p1 = 0;
#pragma unroll
    for (int i = 0; i < 4; ++i) {
        int c = (int)fminf(rintf(v[i] * sc), 127.0f);          // v >= 0 (relu^2)
        p0 |= (uint32_t)(c & 255) << (8 * i);
    }
#pragma unroll
    for (int i = 0; i < 4; ++i) {
        int c = (int)fminf(rintf(v[4 + i] * sc), 127.0f);
        p1 |= (uint32_t)(c & 255) << (8 * i);
    }
    uint2 pk; pk.x = p0; pk.y = p1;
    ((uint2*)rp)[t] = pk;
    if (t == 0) deq[row] = mc / 127.0f;
}

// ---------------- int8 GEMM: C[m][n] = sum_k A[m][k]*B[n][k] ----------------
// 256x256 tile, 512 threads = 8 waves (2M x 4N), wave tile 128x64 as 4x2 of
// v_mfma_i32_32x32x32_i8. Iter = K128 = 2 K-tiles of 64. FINE-GRAINED 8-PHASE
// schedule (m201 template): phase (kt,q) = {2-6 ds_read_b128 || issue exactly
// ONE half-tile global_load_lds for iter tt+1 -> s_barrier -> setprio(1) ->
// 4 MFMA (mt=q block) -> setprio(0) -> [vmcnt(4) at phases 3/7, BEFORE the
// closing barrier] -> s_barrier}. Counted vmcnt: 4-8 staging loads stay in
// flight across barriers; never drained mid-loop. Stage order = consumption
// order (ktile0 halves at phases 0-3, ktile1 at 4-7): a half is issued 5
// phases (~2000 cyc) before first read. vmcnt-before-barrier publishes all
// waves' landings before any wave reads.
// LDS 128 KB: 2 dbuf x [ktile0: A 16K | B 16K][ktile1: A | B], rows 64 B,
// 16 B chunks XOR-swizzled by (row&3), folded into the staging lanes'
// GLOBAL addresses (global_load_lds LDS dest is lane-contiguous).
// XCD-aware map: xcd = blk&7.
template <bool RELU2, typename OutT>
__global__ __launch_bounds__(512, 2) void gemm_i8(
    const int8_t* __restrict__ A, int lda,        // row pitch in bytes
    const int8_t* __restrict__ B, int ldb,
    OutT* __restrict__ O, int ldo,                // pitch in elements
    const float* __restrict__ rowDeq,
    const float* __restrict__ sumPtr,
    const float* __restrict__ bias,
    int K, int nTiles) {
    __shared__ __align__(16) char lds[2][65536];  // 128 KB
    const int t = threadIdx.x;
    const int lane = t & 63;
    const int w = t >> 6;                         // wave 0..7
    const int wm = w >> 2;                        // 0..1
    const int wn = w & 3;                         // 0..3
    const int xcd = blockIdx.x & 7;
    const int sb = blockIdx.x >> 3;
    const int bm = xcd + 8 * (sb / nTiles);
    const int bn = sb % nTiles;
    const long m0 = (long)bm * 256;
    const long n0 = (long)bn * 256;

    v16i acc[4][2];
#pragma unroll
    for (int i = 0; i < 4; ++i)
#pragma unroll
        for (int j = 0; j < 2; ++j) acc[i][j] = (v16i)(0);

    const int r32 = lane & 31;
    const int h = lane >> 5;

    // ---- staging geometry: thread t owns row t>>2 (of a 128-row half),
    //      chunk t&3; source chunk pre-swizzled so LDS(r,c) = K-chunk c^(r&3)
    const int srow = t >> 2;                      // 0..127
    const int scol = ((t & 3) ^ (srow & 3)) * 16;
    const int8_t* srcA = A + (m0 + srow) * (long)lda + scol;
    const int8_t* srcB = B + (n0 + srow) * (long)ldb + scol;
    const long sA2 = 128 * (long)lda;             // half-1 row offset
    const long sB2 = 128 * (long)ldb;

    // ---- fragment-read geometry: global K-chunk (2ks+h), swizzle ^(row&3)
    int cro[2];
#pragma unroll
    for (int ks = 0; ks < 2; ++ks) cro[ks] = ((2 * ks + h) ^ (r32 & 3)) * 16;
    const int abase = wm * 8192 + r32 * 64;       // + q*2048 + cro
    const int bbase = 16384 + wn * 4096 + r32 * 64;  // + nt*2048 + cro

    const int NT = K >> 7;                        // iters of K=128

    // ---- prologue: stage iter 0 (8 halves) into buf 0 ----
#pragma unroll
    for (int p = 0; p < 8; ++p) {
        const int kt = p >> 2, q = p & 3;
        const long kg = (long)kt * 64;
        l_void* d = (l_void*)(lds[0] + kt * 32768 + ((q & 2) ? 16384 : 0) +
                              (q & 1) * 8192 + t * 16);
        const g_void* s = (q & 2) ? (const g_void*)(srcB + (q & 1) * sB2 + kg)
                                  : (const g_void*)(srcA + (q & 1) * sA2 + kg);
        __builtin_amdgcn_global_load_lds(s, d, 16, 0, 0);
    }
    asm volatile("s_waitcnt vmcnt(4)" ::: "memory");  // ktile0 landed (per wave)
    __builtin_amdgcn_s_barrier();                     // publish to all waves
    __builtin_amdgcn_sched_barrier(0);

    for (int tt = 0; tt < NT; ++tt) {
        const char* base0 = lds[tt & 1];
        char* nbuf = lds[(tt & 1) ^ 1];
        const bool pf = (tt + 1 < NT);
        const long kg1 = ((long)(tt + 1)) << 7;
#pragma unroll
        for (int kt = 0; kt < 2; ++kt) {
            const char* base = base0 + kt * 32768;
            v4i bf[2][2];
#pragma unroll
            for (int q = 0; q < 4; ++q) {
                if (q == 0) {
#pragma unroll
                    for (int nt = 0; nt < 2; ++nt)
#pragma unroll
                        for (int ks = 0; ks < 2; ++ks)
                            bf[nt][ks] = *(const v4i*)(base + bbase + nt * 2048 + cro[ks]);
                }
                v4i af[2];
#pragma unroll
                for (int ks = 0; ks < 2; ++ks)
                    af[ks] = *(const v4i*)(base + abase + q * 2048 + cro[ks]);
                if (pf) {                        // stage ONE half of iter tt+1
                    const long kg = kg1 + kt * 64;
                    l_void* d = (l_void*)(nbuf + kt * 32768 + ((q & 2) ? 16384 : 0) +
                                          (q & 1) * 8192 + t * 16);
                    const g_void* s = (q & 2)
                        ? (const g_void*)(srcB + (q & 1) * sB2 + kg)
                        : (const g_void*)(srcA + (q & 1) * sA2 + kg);
                    __builtin_amdgcn_global_load_lds(s, d, 16, 0, 0);
                }
                __builtin_amdgcn_s_barrier();     // opening: phase rhythm
                __builtin_amdgcn_sched_barrier(0);
                __builtin_amdgcn_s_setprio(1);
#pragma unroll
                for (int ks = 0; ks < 2; ++ks)
#pragma unroll
                    for (int nt = 0; nt < 2; ++nt)
                        acc[q][nt] = __builtin_amdgcn_mfma_i32_32x32x32_i8(
                            af[ks], bf[nt][ks], acc[q][nt], 0, 0, 0);
                __builtin_amdgcn_s_setprio(0);
                if (q == 3) {                     // checkpoint BEFORE barrier
                    if (pf) asm volatile("s_waitcnt vmcnt(4)" ::: "memory");
                    else    asm volatile("s_waitcnt vmcnt(0)" ::: "memory");
                }
                __builtin_amdgcn_s_barrier();     // closing
                __builtin_amdgcn_sched_barrier(0);
            }
        }
    }

    // epilogue: C/D layout col = lane&31, row = (reg&3) + 8*(reg>>2) + 4*(lane>>5)
    const float wdeq = fmaxf(sumPtr[0] * (1.0f / 3145728.0f), EPS);
#pragma unroll
    for (int mt = 0; mt < 4; ++mt) {
#pragma unroll
        for (int g = 0; g < 4; ++g) {
#pragma unroll
            for (int rr = 0; rr < 4; ++rr) {
                const long row = m0 + wm * 128 + mt * 32 + g * 8 + h * 4 + rr;
                const float rs = rowDeq[row] * wdeq;
#pragma unroll
                for (int nt = 0; nt < 2; ++nt) {
                    const long col = n0 + wn * 64 + nt * 32 + r32;
                    float val = (float)acc[mt][nt][g * 4 + rr] * rs + bias[col];
                    if (RELU2) {
                        val = fmaxf(val, 0.0f);
                        val = val * val;
                    }
                    O[row * (long)ldo + col] = (OutT)val;
                }
            }
        }
    }
}

// ---------------- launch ----------------
extern "C" void kernel_launch(void* const* d_in, const int* in_sizes, int n_in,
                              void* d_out, int out_size, void* d_ws, size_t ws_size,
                              hipStream_t stream) {
    const float* x      = (const float*)d_in[0];   // [32768,1024]
    const float* up_w   = (const float*)d_in[1];   // [3072,1024]
    const float* up_b   = (const float*)d_in[2];   // [3072]
    const float* down_w = (const float*)d_in[3];   // [1024,3072]
    const float* down_b = (const float*)d_in[4];   // [1024]

    // ws: sums 256B | parts 8KB | qw_dn 3MB | deqh 128KB | hidden bf16 201MB
    char* ws = (char*)d_ws;
    float*  sums   = (float*)ws;
    float*  parts  = (float*)(ws + 256);
    int8_t* qw_dn  = (int8_t*)(ws + 256 + 8192);
    float*  deqh   = (float*)(ws + 256 + 8192 + 3145728);
    __hip_bfloat16* hidden = (__hip_bfloat16*)(ws + 256 + 8192 + 3145728 + 131072);

    // d_out head as phase-1 scratch (dead before GEMM2 writes)
    int8_t* qx    = (int8_t*)d_out;                      // 33.5MB
    int8_t* qw_up = qx + 33554432;                       // 3MB
    float*  deqx  = (float*)(qx + 33554432 + 3145728);   // 128KB

    abs_sum_part_k<<<1024, 256, 0, stream>>>((const float4*)up_w, 786432, parts);
    abs_sum_part_k<<<1024, 256, 0, stream>>>((const float4*)down_w, 786432, parts + 1024);
    abs_sum_final_k<<<2, 256, 0, stream>>>(parts, sums);

    wquant_k<<<3072, 256, 0, stream>>>((const float4*)up_w, (char4*)qw_up, &sums[0]);
    wquant_k<<<3072, 256, 0, stream>>>((const float4*)down_w, (char4*)qw_dn, &sums[1]);
    aquant_k<<<32768, 256, 0, stream>>>((const float4*)x, (char4*)qx, deqx);

    // GEMM1: [32768,1024] x [3072,1024]^T -> hidden bf16 (relu^2 fused)
    // grid: 128 m-tiles x 12 n-tiles = 1536 blocks (divisible by 8 XCDs)
    gemm_i8<true, __hip_bfloat16><<<1536, 512, 0, stream>>>(
        qx, 1024, qw_up, 1024, hidden, 3072, deqx, &sums[0], up_b, 1024, 12);
    // quantize hidden rows in place (int8 overlaid, pitch 6144 B)
    hquant_k<<<32768, 384, 0, stream>>>((unsigned short*)hidden, deqh);
    // GEMM2: [32768,3072] x [1024,3072]^T -> d_out fp32
    // grid: 128 m-tiles x 4 n-tiles = 512 blocks
    gemm_i8<false, float><<<512, 512, 0, stream>>>(
        (const int8_t*)hidden, 6144, qw_dn, 3072, (float*)d_out, 1024,
        deqh, &sums[1], down_b, 3072, 4);
}

// Round 4
// 538.006 us; speedup vs baseline: 1.0946x; 1.0369x over previous
//
#include <hip/hip_runtime.h>
#include <hip/hip_bf16.h>
#include <stdint.h>

#define EPS 1e-5f

typedef int v4i __attribute__((ext_vector_type(4)));
typedef int v16i __attribute__((ext_vector_type(16)));
typedef const __attribute__((address_space(1))) void g_void;
typedef __attribute__((address_space(3))) void l_void;

// ---------------- block reductions ----------------
__device__ inline float block_max_nw(float v, int nw) {
    __shared__ float s[8];
#pragma unroll
    for (int o = 32; o; o >>= 1) v = fmaxf(v, __shfl_xor(v, o, 64));
    if ((threadIdx.x & 63) == 0) s[threadIdx.x >> 6] = v;
    __syncthreads();
    float m = s[0];
    for (int i = 1; i < nw; ++i) m = fmaxf(m, s[i]);
    return m;
}

__device__ inline float block_sum64x4(float v) {
    __shared__ float s[4];
#pragma unroll
    for (int o = 32; o; o >>= 1) v += __shfl_xor(v, o, 64);
    if ((threadIdx.x & 63) == 0) s[threadIdx.x >> 6] = v;
    __syncthreads();
    return s[0] + s[1] + s[2] + s[3];
}

// ---------------- |w| sum: stage 1 (deterministic partials, fixed grid 1024) ----
__global__ __launch_bounds__(256) void abs_sum_part_k(const float4* __restrict__ w,
                                                      int n4, float* __restrict__ part) {
    float s = 0.0f;
    for (int i = blockIdx.x * 256 + threadIdx.x; i < n4; i += 1024 * 256) {
        float4 v = w[i];
        s += fabsf(v.x) + fabsf(v.y) + fabsf(v.z) + fabsf(v.w);
    }
    s = block_sum64x4(s);
    if (threadIdx.x == 0) part[blockIdx.x] = s;
}

// ---------------- |w| sum: stage 2 ----------
__global__ __launch_bounds__(256) void abs_sum_final_k(const float* __restrict__ parts,
                                                       float* __restrict__ sums) {
    const float* p = parts + blockIdx.x * 1024;
    const int t = threadIdx.x;
    float s = p[t] + p[t + 256] + p[t + 512] + p[t + 768];
    s = block_sum64x4(s);
    if (t == 0) sums[blockIdx.x] = s;
}

// ---------------- ternary weight quantization ----------------
__global__ __launch_bounds__(256) void wquant_k(const float4* __restrict__ w,
                                                char4* __restrict__ q,
                                                const float* __restrict__ sum) {
    const float mean = fmaxf(sum[0] * (1.0f / 3145728.0f), EPS);
    const float scale = 1.0f / mean;
    const int i = blockIdx.x * 256 + threadIdx.x;
    float4 v = w[i];
    char4 c;
    c.x = (signed char)(int)fmaxf(fminf(rintf(v.x * scale), 1.0f), -1.0f);
    c.y = (signed char)(int)fmaxf(fminf(rintf(v.y * scale), 1.0f), -1.0f);
    c.z = (signed char)(int)fmaxf(fminf(rintf(v.z * scale), 1.0f), -1.0f);
    c.w = (signed char)(int)fmaxf(fminf(rintf(v.w * scale), 1.0f), -1.0f);
    q[i] = c;
}

// ---------------- per-token int8 quantization of x (rows of 1024 fp32) ----------
__global__ __launch_bounds__(256) void aquant_k(const float4* __restrict__ x,
                                                char4* __restrict__ q,
                                                float* __restrict__ deq) {
    const int row = blockIdx.x, t = threadIdx.x;
    const float4 v = x[(size_t)row * 256 + t];
    float m = fmaxf(fmaxf(fabsf(v.x), fabsf(v.y)), fmaxf(fabsf(v.z), fabsf(v.w)));
    m = block_max_nw(m, 4);
    const float mc = fmaxf(m, EPS);
    const float sc = 127.0f / mc;
    char4 c;
    c.x = (signed char)(int)fmaxf(fminf(rintf(v.x * sc), 127.0f), -128.0f);
    c.y = (signed char)(int)fmaxf(fminf(rintf(v.y * sc), 127.0f), -128.0f);
    c.z = (signed char)(int)fmaxf(fminf(rintf(v.z * sc), 127.0f), -128.0f);
    c.w = (signed char)(int)fmaxf(fminf(rintf(v.w * sc), 127.0f), -128.0f);
    q[(size_t)row * 256 + t] = c;
    if (t == 0) deq[row] = mc / 127.0f;
}

// ---------------- per-token quant of bf16 hidden rows (3072), IN PLACE ----------
__global__ __launch_bounds__(384) void hquant_k(unsigned short* __restrict__ hid,
                                                float* __restrict__ deq) {
    const size_t row = blockIdx.x;
    const int t = threadIdx.x;
    unsigned short* rp = hid + row * 3072;
    const uint4 u = ((const uint4*)rp)[t];
    float v[8];
    {
        uint32_t uu[4] = {u.x, u.y, u.z, u.w};
#pragma unroll
        for (int i = 0; i < 4; ++i) {
            uint32_t lo = uu[i] << 16, hi = uu[i] & 0xFFFF0000u;
            v[2 * i]     = __uint_as_float(lo);
            v[2 * i + 1] = __uint_as_float(hi);
        }
    }
    float m = 0.0f;
#pragma unroll
    for (int i = 0; i < 8; ++i) m = fmaxf(m, fabsf(v[i]));
    m = block_max_nw(m, 6);   // contains __syncthreads(): loads done before stores
    const float mc = fmaxf(m, EPS);
    const float sc = 127.0f / mc;
    uint32_t p0 = 0, p1 = 0;
#pragma unroll
    for (int i = 0; i < 4; ++i) {
        int c = (int)fminf(rintf(v[i] * sc), 127.0f);          // v >= 0 (relu^2)
        p0 |= (uint32_t)(c & 255) << (8 * i);
    }
#pragma unroll
    for (int i = 0; i < 4; ++i) {
        int c = (int)fminf(rintf(v[4 + i] * sc), 127.0f);
        p1 |= (uint32_t)(c & 255) << (8 * i);
    }
    uint2 pk; pk.x = p0; pk.y = p1;
    ((uint2*)rp)[t] = pk;
    if (t == 0) deq[row] = mc / 127.0f;
}

// ---------------- int8 GEMM: C[m][n] = sum_k A[m][k]*B[n][k] ----------------
// R0 geometry (the measured best): 128(m)x256(n) tile, 256 threads = 4 waves
// (2x2), wave tile 64x128 as 2x4 of v_mfma_i32_32x32x32_i8 — kept because it
// runs 2 blocks/CU (cross-block pipe overlap). NEW: BK=64 RING-3 LDS
// (3 x 24 KB = 72 KB -> still 2 blocks/CU) with counted vmcnt: stage tile
// tt+2 at top of iter tt, ONE barrier per iter, end-of-iter vmcnt(6) — tile
// tt+1 certified landed while tile tt+2's 6 loads stay in flight across the
// barrier. Mid-loop never drains to 0 (that drain was R0's per-iter
// serialization point). Safety (R2-proven argument): the end-of-iter barrier
// certifies block-wide reads of buf[t%3] before iter t+3 overwrites it, and
// every wave's ds_reads retire before its MFMAs issue, which precede the
// barrier. LDS rows 64 B; 16 B chunks XOR-swizzled by (row>>1)&3 (the
// R0/R2-proven 9.4M-floor scheme), folded into staging lanes' GLOBAL
// addresses (global_load_lds LDS dest is lane-contiguous). XCD map: blk&7.
template <bool RELU2, typename OutT>
__global__ __launch_bounds__(256, 2) void gemm_i8(
    const int8_t* __restrict__ A, int lda,        // row pitch in bytes
    const int8_t* __restrict__ B, int ldb,
    OutT* __restrict__ O, int ldo,                // pitch in elements
    const float* __restrict__ rowDeq,
    const float* __restrict__ sumPtr,
    const float* __restrict__ bias,
    int K, int nTiles) {
    __shared__ __align__(16) char lds[3][24576];  // per buf: A 8K @0 | B 16K @8192
    const int t = threadIdx.x;
    const int lane = t & 63;
    const int w = t >> 6;                         // wave 0..3
    const int xcd = blockIdx.x & 7;
    const int sb = blockIdx.x >> 3;
    const int bm = xcd + 8 * (sb / nTiles);
    const int bn = sb % nTiles;
    const long m0 = (long)bm * 128;
    const long n0 = (long)bn * 256;

    v16i acc[2][4];
#pragma unroll
    for (int i = 0; i < 2; ++i)
#pragma unroll
        for (int j = 0; j < 4; ++j) acc[i][j] = (v16i)(0);

    const int mloc = (w >> 1) * 64;
    const int nloc = (w & 1) * 128;
    const int r32 = lane & 31;
    const int h = lane >> 5;

    // ---- staging geometry: 1 KB per instr = 16 rows x 64 B; lane l covers
    //      row srow = l>>2, chunk l&3; source chunk pre-swizzled by (row>>1)&3
    const int srow = lane >> 2;
    const int sc = ((lane & 3) ^ ((lane >> 3) & 3)) * 16;
    const int8_t* paS = A + (m0 + w * 32 + srow) * (long)lda + sc;  // 2 instr: +0,+16 rows
    const int8_t* pbS = B + (n0 + w * 64 + srow) * (long)ldb + sc;  // 4 instr: +0..+48

    // ---- fragment-read geometry: chunk (2ks+h) ^ ((row>>1)&3) ----
    int cro[2];
#pragma unroll
    for (int ks = 0; ks < 2; ++ks) cro[ks] = ((2 * ks + h) ^ ((r32 >> 1) & 3)) * 16;

    const int NT = K >> 6;                        // K-tiles of 64 (>= 16 here)

    auto STAGE = [&](int tt) {                    // 6 global_load_lds per wave
        char* buf = lds[tt % 3];
        const long ko = (long)tt << 6;
#pragma unroll
        for (int r = 0; r < 2; ++r)
            __builtin_amdgcn_global_load_lds(
                (g_void*)(paS + (long)(r * 16) * lda + ko),
                (l_void*)(buf + w * 2048 + r * 1024 + lane * 16), 16, 0, 0);
#pragma unroll
        for (int r = 0; r < 4; ++r)
            __builtin_amdgcn_global_load_lds(
                (g_void*)(pbS + (long)(r * 16) * ldb + ko),
                (l_void*)(buf + 8192 + w * 4096 + r * 1024 + lane * 16), 16, 0, 0);
    };

    // prologue: tiles 0,1 in flight (12 loads); wait tile 0 only (6 remain)
    STAGE(0);
    STAGE(1);
    asm volatile("s_waitcnt vmcnt(6)" ::: "memory");
    __builtin_amdgcn_s_barrier();
    __builtin_amdgcn_sched_barrier(0);

    for (int tt = 0; tt < NT; ++tt) {
        const char* buf = lds[tt % 3];
        const bool pf = (tt + 2 < NT);
        if (pf) STAGE(tt + 2);                    // -> buf[(tt+2)%3], freed at tt-1
        __builtin_amdgcn_sched_barrier(0);        // keep prefetch issue at top
#pragma unroll
        for (int ks = 0; ks < 2; ++ks) {
            v4i af[2], bf[4];
#pragma unroll
            for (int mt = 0; mt < 2; ++mt)
                af[mt] = *(const v4i*)(buf + (mloc + mt * 32 + r32) * 64 + cro[ks]);
#pragma unroll
            for (int nt = 0; nt < 4; ++nt)
                bf[nt] = *(const v4i*)(buf + 8192 + (nloc + nt * 32 + r32) * 64 + cro[ks]);
            __builtin_amdgcn_s_setprio(1);
#pragma unroll
            for (int mt = 0; mt < 2; ++mt)
#pragma unroll
                for (int nt = 0; nt < 4; ++nt)
                    acc[mt][nt] = __builtin_amdgcn_mfma_i32_32x32x32_i8(
                        af[mt], bf[nt], acc[mt][nt], 0, 0, 0);
            __builtin_amdgcn_s_setprio(0);
        }
        if (tt + 1 < NT) {
            // tile tt+1 must be landed; tile tt+2's 6 loads stay in flight
            if (pf) asm volatile("s_waitcnt vmcnt(6)" ::: "memory");
            else    asm volatile("s_waitcnt vmcnt(0)" ::: "memory");
            __builtin_amdgcn_s_barrier();
            __builtin_amdgcn_sched_barrier(0);
        }
    }

    // epilogue: C/D layout col = lane&31, row = (reg&3) + 8*(reg>>2) + 4*(lane>>5)
    const float wdeq = fmaxf(sumPtr[0] * (1.0f / 3145728.0f), EPS);
#pragma unroll
    for (int mt = 0; mt < 2; ++mt) {
#pragma unroll
        for (int g = 0; g < 4; ++g) {
#pragma unroll
            for (int rr = 0; rr < 4; ++rr) {
                const long row = m0 + mloc + mt * 32 + g * 8 + h * 4 + rr;
                const float rs = rowDeq[row] * wdeq;
#pragma unroll
                for (int nt = 0; nt < 4; ++nt) {
                    const long col = n0 + nloc + nt * 32 + r32;
                    float val = (float)acc[mt][nt][g * 4 + rr] * rs + bias[col];
                    if (RELU2) {
                        val = fmaxf(val, 0.0f);
                        val = val * val;
                    }
                    O[row * (long)ldo + col] = (OutT)val;
                }
            }
        }
    }
}

// ---------------- launch ----------------
extern "C" void kernel_launch(void* const* d_in, const int* in_sizes, int n_in,
                              void* d_out, int out_size, void* d_ws, size_t ws_size,
                              hipStream_t stream) {
    const float* x      = (const float*)d_in[0];   // [32768,1024]
    const float* up_w   = (const float*)d_in[1];   // [3072,1024]
    const float* up_b   = (const float*)d_in[2];   // [3072]
    const float* down_w = (const float*)d_in[3];   // [1024,3072]
    const float* down_b = (const float*)d_in[4];   // [1024]

    // ws: sums 256B | parts 8KB | qw_dn 3MB | deqh 128KB | hidden bf16 201MB
    char* ws = (char*)d_ws;
    float*  sums   = (float*)ws;
    float*  parts  = (float*)(ws + 256);
    int8_t* qw_dn  = (int8_t*)(ws + 256 + 8192);
    float*  deqh   = (float*)(ws + 256 + 8192 + 3145728);
    __hip_bfloat16* hidden = (__hip_bfloat16*)(ws + 256 + 8192 + 3145728 + 131072);

    // d_out head as phase-1 scratch (dead before GEMM2 writes)
    int8_t* qx    = (int8_t*)d_out;                      // 33.5MB
    int8_t* qw_up = qx + 33554432;                       // 3MB
    float*  deqx  = (float*)(qx + 33554432 + 3145728);   // 128KB

    abs_sum_part_k<<<1024, 256, 0, stream>>>((const float4*)up_w, 786432, parts);
    abs_sum_part_k<<<1024, 256, 0, stream>>>((const float4*)down_w, 786432, parts + 1024);
    abs_sum_final_k<<<2, 256, 0, stream>>>(parts, sums);

    wquant_k<<<3072, 256, 0, stream>>>((const float4*)up_w, (char4*)qw_up, &sums[0]);
    wquant_k<<<3072, 256, 0, stream>>>((const float4*)down_w, (char4*)qw_dn, &sums[1]);
    aquant_k<<<32768, 256, 0, stream>>>((const float4*)x, (char4*)qx, deqx);

    // GEMM1: [32768,1024] x [3072,1024]^T -> hidden bf16 (relu^2 fused)
    // grid: 256 m-tiles x 12 n-tiles = 3072 blocks
    gemm_i8<true, __hip_bfloat16><<<3072, 256, 0, stream>>>(
        qx, 1024, qw_up, 1024, hidden, 3072, deqx, &sums[0], up_b, 1024, 12);
    // quantize hidden rows in place (int8 overlaid, pitch 6144 B)
    hquant_k<<<32768, 384, 0, stream>>>((unsigned short*)hidden, deqh);
    // GEMM2: [32768,3072] x [1024,3072]^T -> d_out fp32
    // grid: 256 m-tiles x 4 n-tiles = 1024 blocks
    gemm_i8<false, float><<<1024, 256, 0, stream>>>(
        (const int8_t*)hidden, 6144, qw_dn, 3072, (float*)d_out, 1024,
        deqh, &sums[1], down_b, 3072, 4);
}

// Round 5
// 523.671 us; speedup vs baseline: 1.1245x; 1.0274x over previous
//
#include <hip/hip_runtime.h>
#include <hip/hip_bf16.h>
#include <stdint.h>

#define EPS 1e-5f

typedef int v4i __attribute__((ext_vector_type(4)));
typedef int v16i __attribute__((ext_vector_type(16)));
typedef const __attribute__((address_space(1))) void g_void;
typedef __attribute__((address_space(3))) void l_void;

// ---------------- block reductions ----------------
__device__ inline float block_sum64x4(float v) {
    __shared__ float s[4];
#pragma unroll
    for (int o = 32; o; o >>= 1) v += __shfl_xor(v, o, 64);
    if ((threadIdx.x & 63) == 0) s[threadIdx.x >> 6] = v;
    __syncthreads();
    return s[0] + s[1] + s[2] + s[3];
}

// ---------------- |w| sum: stage 1 (deterministic partials, fixed grid 1024) ----
__global__ __launch_bounds__(256) void abs_sum_part_k(const float4* __restrict__ w,
                                                      int n4, float* __restrict__ part) {
    float s = 0.0f;
    for (int i = blockIdx.x * 256 + threadIdx.x; i < n4; i += 1024 * 256) {
        float4 v = w[i];
        s += fabsf(v.x) + fabsf(v.y) + fabsf(v.z) + fabsf(v.w);
    }
    s = block_sum64x4(s);
    if (threadIdx.x == 0) part[blockIdx.x] = s;
}

// ---------------- |w| sum: stage 2 ----------
__global__ __launch_bounds__(256) void abs_sum_final_k(const float* __restrict__ parts,
                                                       float* __restrict__ sums) {
    const float* p = parts + blockIdx.x * 1024;
    const int t = threadIdx.x;
    float s = p[t] + p[t + 256] + p[t + 512] + p[t + 768];
    s = block_sum64x4(s);
    if (t == 0) sums[blockIdx.x] = s;
}

// ---------------- ternary weight quantization ----------------
__global__ __launch_bounds__(256) void wquant_k(const float4* __restrict__ w,
                                                char4* __restrict__ q,
                                                const float* __restrict__ sum) {
    const float mean = fmaxf(sum[0] * (1.0f / 3145728.0f), EPS);
    const float scale = 1.0f / mean;
    const int i = blockIdx.x * 256 + threadIdx.x;
    float4 v = w[i];
    char4 c;
    c.x = (signed char)(int)fmaxf(fminf(rintf(v.x * scale), 1.0f), -1.0f);
    c.y = (signed char)(int)fmaxf(fminf(rintf(v.y * scale), 1.0f), -1.0f);
    c.z = (signed char)(int)fmaxf(fminf(rintf(v.z * scale), 1.0f), -1.0f);
    c.w = (signed char)(int)fmaxf(fminf(rintf(v.w * scale), 1.0f), -1.0f);
    q[i] = c;
}

// ---------------- per-token int8 quant of x: WAVE-PER-ROW, sync-free ----------
// block 256 = 4 waves = 4 rows; grid 8192. Lane j-strided loads (coalesced),
// shfl_xor max reduce, no LDS, no barrier.
__global__ __launch_bounds__(256) void aquant_k(const float4* __restrict__ x,
                                                char4* __restrict__ q,
                                                float* __restrict__ deq) {
    const int wv = threadIdx.x >> 6, lane = threadIdx.x & 63;
    const size_t row = (size_t)blockIdx.x * 4 + wv;
    const float4* xr = x + row * 256;
    float4 v[4];
    float m = 0.0f;
#pragma unroll
    for (int j = 0; j < 4; ++j) {
        v[j] = xr[j * 64 + lane];
        m = fmaxf(m, fmaxf(fmaxf(fabsf(v[j].x), fabsf(v[j].y)),
                           fmaxf(fabsf(v[j].z), fabsf(v[j].w))));
    }
#pragma unroll
    for (int o = 32; o; o >>= 1) m = fmaxf(m, __shfl_xor(m, o, 64));
    const float mc = fmaxf(m, EPS);
    const float sc = 127.0f / mc;
    char4* qr = q + row * 256;
#pragma unroll
    for (int j = 0; j < 4; ++j) {
        char4 c;
        c.x = (signed char)(int)fmaxf(fminf(rintf(v[j].x * sc), 127.0f), -128.0f);
        c.y = (signed char)(int)fmaxf(fminf(rintf(v[j].y * sc), 127.0f), -128.0f);
        c.z = (signed char)(int)fmaxf(fminf(rintf(v[j].z * sc), 127.0f), -128.0f);
        c.w = (signed char)(int)fmaxf(fminf(rintf(v[j].w * sc), 127.0f), -128.0f);
        qr[j * 64 + lane] = c;
    }
    if (lane == 0) deq[row] = mc / 127.0f;
}

// ---------------- per-token quant of bf16 hidden rows (3072), IN PLACE -------
// WAVE-PER-ROW, sync-free: block 256 = 4 waves = 4 rows; grid 8192. In-place
// safety: each wave's loads complete (register dependency) before its stores.
__global__ __launch_bounds__(256) void hquant_k(unsigned short* __restrict__ hid,
                                                float* __restrict__ deq) {
    const int wv = threadIdx.x >> 6, lane = threadIdx.x & 63;
    const size_t row = (size_t)blockIdx.x * 4 + wv;
    unsigned short* rp = hid + row * 3072;
    float vals[48];
    float m = 0.0f;
#pragma unroll
    for (int j = 0; j < 6; ++j) {
        const uint4 u = ((const uint4*)rp)[j * 64 + lane];
        uint32_t uu[4] = {u.x, u.y, u.z, u.w};
#pragma unroll
        for (int i = 0; i < 4; ++i) {
            vals[j * 8 + 2 * i]     = __uint_as_float(uu[i] << 16);
            vals[j * 8 + 2 * i + 1] = __uint_as_float(uu[i] & 0xFFFF0000u);
        }
#pragma unroll
        for (int i = 0; i < 8; ++i) m = fmaxf(m, vals[j * 8 + i]);  // vals >= 0
    }
#pragma unroll
    for (int o = 32; o; o >>= 1) m = fmaxf(m, __shfl_xor(m, o, 64));
    const float mc = fmaxf(m, EPS);
    const float sc = 127.0f / mc;
#pragma unroll
    for (int j = 0; j < 6; ++j) {
        uint32_t p0 = 0, p1 = 0;
#pragma unroll
        for (int i = 0; i < 4; ++i) {
            int c = (int)fminf(rintf(vals[j * 8 + i] * sc), 127.0f);
            p0 |= (uint32_t)(c & 255) << (8 * i);
        }
#pragma unroll
        for (int i = 0; i < 4; ++i) {
            int c = (int)fminf(rintf(vals[j * 8 + 4 + i] * sc), 127.0f);
            p1 |= (uint32_t)(c & 255) << (8 * i);
        }
        uint2 pk; pk.x = p0; pk.y = p1;
        ((uint2*)rp)[j * 64 + lane] = pk;
    }
    if (lane == 0) deq[row] = mc / 127.0f;
}

// ---------------- int8 GEMM: C[m][n] = sum_k A[m][k]*B[n][k] ----------------
// R0 geometry (measured best): 128(m)x256(n), 256 thr = 4 waves (2x2), wave
// tile 64x128 as 2x4 of v_mfma_i32_32x32x32_i8; 2 blocks/CU. Ring-3 BK=64
// LDS (72 KB) with counted vmcnt(6) (R4 structure, passed twice).
// NEW: K is a TEMPLATE param and the K-loop is FULLY UNROLLED -> tt%3 buffer
// indices, all ds_read offsets, and all global_load_lds K-offsets become
// compile-time immediates off loop-invariant per-lane bases. Per-iter VALU
// ~0 (was 27% busy = 533 cyc/iter of address recompute INSIDE the
// ds_read->MFMA chain, serializing the LDS/VALU/MFMA pipes: 39%+27%+26%=92%).
// LDS rows 64 B; 16 B chunks XOR-swizzled by (row>>1)&3, folded into staging
// lanes' GLOBAL addresses. XCD map: blk&7. lgkmcnt(0) before each barrier is
// free (reads already consumed by MFMAs) and makes the ring overwrite safe.
template <int K, int NTILES, bool RELU2, typename OutT>
__global__ __launch_bounds__(256, 2) void gemm_i8(
    const int8_t* __restrict__ A, int lda,        // row pitch in bytes
    const int8_t* __restrict__ B, int ldb,
    OutT* __restrict__ O, int ldo,                // pitch in elements
    const float* __restrict__ rowDeq,
    const float* __restrict__ sumPtr,
    const float* __restrict__ bias) {
    constexpr int NT = K >> 6;                    // K-tiles of 64
    __shared__ __align__(16) char lds[3][24576];  // per buf: A 8K @0 | B 16K @8192
    const int t = threadIdx.x;
    const int lane = t & 63;
    const int w = t >> 6;                         // wave 0..3
    const int xcd = blockIdx.x & 7;
    const int sb = blockIdx.x >> 3;
    const int bm = xcd + 8 * (sb / NTILES);
    const int bn = sb % NTILES;
    const long m0 = (long)bm * 128;
    const long n0 = (long)bn * 256;

    v16i acc[2][4];
#pragma unroll
    for (int i = 0; i < 2; ++i)
#pragma unroll
        for (int j = 0; j < 4; ++j) acc[i][j] = (v16i)(0);

    const int mloc = (w >> 1) * 64;
    const int nloc = (w & 1) * 128;
    const int r32 = lane & 31;
    const int h = lane >> 5;

    // ---- staging bases (loop-invariant): 6 pointers, K-advance via imm ----
    const int srow = lane >> 2;
    const int scS = ((lane & 3) ^ ((lane >> 3) & 3)) * 16;  // pre-swizzled chunk
    const int8_t* paS0 = A + (m0 + w * 32 + srow) * (long)lda + scS;
    const int8_t* paS1 = paS0 + 16 * (long)lda;
    const int8_t* pbS0 = B + (n0 + w * 64 + srow) * (long)ldb + scS;
    const int8_t* pbS1 = pbS0 + 16 * (long)ldb;
    const int8_t* pbS2 = pbS0 + 32 * (long)ldb;
    const int8_t* pbS3 = pbS0 + 48 * (long)ldb;

    // ---- fragment-read bases (loop-invariant, per-lane): chunk (2ks+h)^((r>>1)&3)
    const int swz = (r32 >> 1) & 3;
    const char* rdA0 = &lds[0][0] + (mloc + r32) * 64 + ((h ^ swz) * 16);
    const char* rdA1 = &lds[0][0] + (mloc + r32) * 64 + (((2 + h) ^ swz) * 16);
    const char* rdB0 = &lds[0][0] + 8192 + (nloc + r32) * 64 + ((h ^ swz) * 16);
    const char* rdB1 = &lds[0][0] + 8192 + (nloc + r32) * 64 + (((2 + h) ^ swz) * 16);

    auto STAGE = [&](int tt) {                    // tt compile-time after unroll
        char* buf = &lds[0][0] + (tt % 3) * 24576;
        const long ko = (long)tt << 6;
        __builtin_amdgcn_global_load_lds((g_void*)(paS0 + ko),
                                         (l_void*)(buf + w * 2048), 16, 0, 0);
        __builtin_amdgcn_global_load_lds((g_void*)(paS1 + ko),
                                         (l_void*)(buf + w * 2048 + 1024), 16, 0, 0);
        __builtin_amdgcn_global_load_lds((g_void*)(pbS0 + ko),
                                         (l_void*)(buf + 8192 + w * 4096), 16, 0, 0);
        __builtin_amdgcn_global_load_lds((g_void*)(pbS1 + ko),
                                         (l_void*)(buf + 8192 + w * 4096 + 1024), 16, 0, 0);
        __builtin_amdgcn_global_load_lds((g_void*)(pbS2 + ko),
                                         (l_void*)(buf + 8192 + w * 4096 + 2048), 16, 0, 0);
        __builtin_amdgcn_global_load_lds((g_void*)(pbS3 + ko),
                                         (l_void*)(buf + 8192 + w * 4096 + 3072), 16, 0, 0);
    };

    // prologue: tiles 0,1 in flight (12 loads); wait tile 0 only (6 remain)
    STAGE(0);
    STAGE(1);
    asm volatile("s_waitcnt vmcnt(6)" ::: "memory");
    __builtin_amdgcn_s_barrier();
    __builtin_amdgcn_sched_barrier(0);

#pragma unroll
    for (int tt = 0; tt < NT; ++tt) {
        const int bo = (tt % 3) * 24576;          // compile-time after unroll
        if (tt + 2 < NT) STAGE(tt + 2);           // -> buf[(tt+2)%3]
        v4i af[2][2], bf[2][4];                   // [ks][...]
#pragma unroll
        for (int ks = 0; ks < 2; ++ks) {
            const char* rA = ks ? rdA1 : rdA0;
            const char* rB = ks ? rdB1 : rdB0;
#pragma unroll
            for (int mt = 0; mt < 2; ++mt)
                af[ks][mt] = *(const v4i*)(rA + bo + mt * 2048);
#pragma unroll
            for (int nt = 0; nt < 4; ++nt)
                bf[ks][nt] = *(const v4i*)(rB + bo + nt * 2048);
        }
#pragma unroll
        for (int ks = 0; ks < 2; ++ks)
#pragma unroll
            for (int mt = 0; mt < 2; ++mt)
#pragma unroll
                for (int nt = 0; nt < 4; ++nt)
                    acc[mt][nt] = __builtin_amdgcn_mfma_i32_32x32x32_i8(
                        af[ks][mt], bf[ks][nt], acc[mt][nt], 0, 0, 0);
        if (tt + 1 < NT) {
            // tile tt+1 must be landed; tile tt+2's 6 loads stay in flight
            if (tt + 2 < NT) asm volatile("s_waitcnt vmcnt(6) lgkmcnt(0)" ::: "memory");
            else             asm volatile("s_waitcnt vmcnt(0) lgkmcnt(0)" ::: "memory");
            __builtin_amdgcn_s_barrier();
            __builtin_amdgcn_sched_barrier(0);
        }
    }

    // epilogue: C/D layout col = lane&31, row = (reg&3) + 8*(reg>>2) + 4*(lane>>5)
    const float wdeq = fmaxf(sumPtr[0] * (1.0f / 3145728.0f), EPS);
#pragma unroll
    for (int mt = 0; mt < 2; ++mt) {
#pragma unroll
        for (int g = 0; g < 4; ++g) {
#pragma unroll
            for (int rr = 0; rr < 4; ++rr) {
                const long row = m0 + mloc + mt * 32 + g * 8 + h * 4 + rr;
                const float rs = rowDeq[row] * wdeq;
#pragma unroll
                for (int nt = 0; nt < 4; ++nt) {
                    const long col = n0 + nloc + nt * 32 + r32;
                    float val = (float)acc[mt][nt][g * 4 + rr] * rs + bias[col];
                    if (RELU2) {
                        val = fmaxf(val, 0.0f);
                        val = val * val;
                    }
                    O[row * (long)ldo + col] = (OutT)val;
                }
            }
        }
    }
}

// ---------------- launch ----------------
extern "C" void kernel_launch(void* const* d_in, const int* in_sizes, int n_in,
                              void* d_out, int out_size, void* d_ws, size_t ws_size,
                              hipStream_t stream) {
    const float* x      = (const float*)d_in[0];   // [32768,1024]
    const float* up_w   = (const float*)d_in[1];   // [3072,1024]
    const float* up_b   = (const float*)d_in[2];   // [3072]
    const float* down_w = (const float*)d_in[3];   // [1024,3072]
    const float* down_b = (const float*)d_in[4];   // [1024]

    // ws: sums 256B | parts 8KB | qw_dn 3MB | deqh 128KB | hidden bf16 201MB
    char* ws = (char*)d_ws;
    float*  sums   = (float*)ws;
    float*  parts  = (float*)(ws + 256);
    int8_t* qw_dn  = (int8_t*)(ws + 256 + 8192);
    float*  deqh   = (float*)(ws + 256 + 8192 + 3145728);
    __hip_bfloat16* hidden = (__hip_bfloat16*)(ws + 256 + 8192 + 3145728 + 131072);

    // d_out head as phase-1 scratch (dead before GEMM2 writes)
    int8_t* qx    = (int8_t*)d_out;                      // 33.5MB
    int8_t* qw_up = qx + 33554432;                       // 3MB
    float*  deqx  = (float*)(qx + 33554432 + 3145728);   // 128KB

    abs_sum_part_k<<<1024, 256, 0, stream>>>((const float4*)up_w, 786432, parts);
    abs_sum_part_k<<<1024, 256, 0, stream>>>((const float4*)down_w, 786432, parts + 1024);
    abs_sum_final_k<<<2, 256, 0, stream>>>(parts, sums);

    wquant_k<<<3072, 256, 0, stream>>>((const float4*)up_w, (char4*)qw_up, &sums[0]);
    wquant_k<<<3072, 256, 0, stream>>>((const float4*)down_w, (char4*)qw_dn, &sums[1]);
    aquant_k<<<8192, 256, 0, stream>>>((const float4*)x, (char4*)qx, deqx);

    // GEMM1: [32768,1024] x [3072,1024]^T -> hidden bf16 (relu^2 fused)
    // grid: 256 m-tiles x 12 n-tiles = 3072 blocks
    gemm_i8<1024, 12, true, __hip_bfloat16><<<3072, 256, 0, stream>>>(
        qx, 1024, qw_up, 1024, hidden, 3072, deqx, &sums[0], up_b);
    // quantize hidden rows in place (int8 overlaid, pitch 6144 B)
    hquant_k<<<8192, 256, 0, stream>>>((unsigned short*)hidden, deqh);
    // GEMM2: [32768,3072] x [1024,3072]^T -> d_out fp32
    // grid: 256 m-tiles x 4 n-tiles = 1024 blocks
    gemm_i8<3072, 4, false, float><<<1024, 256, 0, stream>>>(
        (const int8_t*)hidden, 6144, qw_dn, 3072, (float*)d_out, 1024,
        deqh, &sums[1], down_b);
}

// Round 6
// 518.189 us; speedup vs baseline: 1.1364x; 1.0106x over previous
//
#include <hip/hip_runtime.h>
#include <hip/hip_bf16.h>
#include <stdint.h>

#define EPS 1e-5f

typedef int v4i __attribute__((ext_vector_type(4)));
typedef int v16i __attribute__((ext_vector_type(16)));
typedef const __attribute__((address_space(1))) void g_void;
typedef __attribute__((address_space(3))) void l_void;

// ---------------- block reductions ----------------
__device__ inline float block_sum64x4(float v) {
    __shared__ float s[4];
#pragma unroll
    for (int o = 32; o; o >>= 1) v += __shfl_xor(v, o, 64);
    if ((threadIdx.x & 63) == 0) s[threadIdx.x >> 6] = v;
    __syncthreads();
    return s[0] + s[1] + s[2] + s[3];
}

// ---------------- |w| sums for BOTH weights in one launch ----------------
// grid 2048: blocks 0..1023 -> up_w partials [0..1023], 1024..2047 -> down_w
// partials [1024..2047]. Deterministic fixed-grid partials.
__global__ __launch_bounds__(256) void abs_sum_part_k(const float4* __restrict__ w0,
                                                      const float4* __restrict__ w1,
                                                      float* __restrict__ part) {
    const int half = blockIdx.x >> 10;            // 0 or 1
    const float4* w = half ? w1 : w0;
    float s = 0.0f;
    for (int i = (blockIdx.x & 1023) * 256 + threadIdx.x; i < 786432; i += 1024 * 256) {
        float4 v = w[i];
        s += fabsf(v.x) + fabsf(v.y) + fabsf(v.z) + fabsf(v.w);
    }
    s = block_sum64x4(s);
    if (threadIdx.x == 0) part[blockIdx.x] = s;
}

// ---------------- |w| sum: stage 2 ----------
__global__ __launch_bounds__(256) void abs_sum_final_k(const float* __restrict__ parts,
                                                       float* __restrict__ sums) {
    const float* p = parts + blockIdx.x * 1024;
    const int t = threadIdx.x;
    float s = p[t] + p[t + 256] + p[t + 512] + p[t + 768];
    s = block_sum64x4(s);
    if (t == 0) sums[blockIdx.x] = s;
}

// ---------------- ternary weight quantization, BOTH weights one launch --------
// grid 6144: blocks 0..3071 -> up_w (sums[0]) -> q0; 3072..6143 -> down_w -> q1.
__global__ __launch_bounds__(256) void wquant_k(const float4* __restrict__ w0,
                                                const float4* __restrict__ w1,
                                                char4* __restrict__ q0,
                                                char4* __restrict__ q1,
                                                const float* __restrict__ sums) {
    const int half = (blockIdx.x >= 3072) ? 1 : 0;
    const float4* w = half ? w1 : w0;
    char4* q = half ? q1 : q0;
    const float mean = fmaxf(sums[half] * (1.0f / 3145728.0f), EPS);
    const float scale = 1.0f / mean;
    const int i = (blockIdx.x - half * 3072) * 256 + threadIdx.x;
    float4 v = w[i];
    char4 c;
    c.x = (signed char)(int)fmaxf(fminf(rintf(v.x * scale), 1.0f), -1.0f);
    c.y = (signed char)(int)fmaxf(fminf(rintf(v.y * scale), 1.0f), -1.0f);
    c.z = (signed char)(int)fmaxf(fminf(rintf(v.z * scale), 1.0f), -1.0f);
    c.w = (signed char)(int)fmaxf(fminf(rintf(v.w * scale), 1.0f), -1.0f);
    q[i] = c;
}

// ---------------- per-token int8 quant of x: WAVE-PER-ROW, sync-free ----------
__global__ __launch_bounds__(256) void aquant_k(const float4* __restrict__ x,
                                                char4* __restrict__ q,
                                                float* __restrict__ deq) {
    const int wv = threadIdx.x >> 6, lane = threadIdx.x & 63;
    const size_t row = (size_t)blockIdx.x * 4 + wv;
    const float4* xr = x + row * 256;
    float4 v[4];
    float m = 0.0f;
#pragma unroll
    for (int j = 0; j < 4; ++j) {
        v[j] = xr[j * 64 + lane];
        m = fmaxf(m, fmaxf(fmaxf(fabsf(v[j].x), fabsf(v[j].y)),
                           fmaxf(fabsf(v[j].z), fabsf(v[j].w))));
    }
#pragma unroll
    for (int o = 32; o; o >>= 1) m = fmaxf(m, __shfl_xor(m, o, 64));
    const float mc = fmaxf(m, EPS);
    const float sc = 127.0f / mc;
    char4* qr = q + row * 256;
#pragma unroll
    for (int j = 0; j < 4; ++j) {
        char4 c;
        c.x = (signed char)(int)fmaxf(fminf(rintf(v[j].x * sc), 127.0f), -128.0f);
        c.y = (signed char)(int)fmaxf(fminf(rintf(v[j].y * sc), 127.0f), -128.0f);
        c.z = (signed char)(int)fmaxf(fminf(rintf(v[j].z * sc), 127.0f), -128.0f);
        c.w = (signed char)(int)fmaxf(fminf(rintf(v[j].w * sc), 127.0f), -128.0f);
        qr[j * 64 + lane] = c;
    }
    if (lane == 0) deq[row] = mc / 127.0f;
}

// ---------------- per-token quant of bf16 hidden rows (3072), IN PLACE -------
// WAVE-PER-ROW, sync-free. In-place safety: wave's loads complete (register
// dependency) before its stores.
__global__ __launch_bounds__(256) void hquant_k(unsigned short* __restrict__ hid,
                                                float* __restrict__ deq) {
    const int wv = threadIdx.x >> 6, lane = threadIdx.x & 63;
    const size_t row = (size_t)blockIdx.x * 4 + wv;
    unsigned short* rp = hid + row * 3072;
    float vals[48];
    float m = 0.0f;
#pragma unroll
    for (int j = 0; j < 6; ++j) {
        const uint4 u = ((const uint4*)rp)[j * 64 + lane];
        uint32_t uu[4] = {u.x, u.y, u.z, u.w};
#pragma unroll
        for (int i = 0; i < 4; ++i) {
            vals[j * 8 + 2 * i]     = __uint_as_float(uu[i] << 16);
            vals[j * 8 + 2 * i + 1] = __uint_as_float(uu[i] & 0xFFFF0000u);
        }
#pragma unroll
        for (int i = 0; i < 8; ++i) m = fmaxf(m, vals[j * 8 + i]);  // vals >= 0
    }
#pragma unroll
    for (int o = 32; o; o >>= 1) m = fmaxf(m, __shfl_xor(m, o, 64));
    const float mc = fmaxf(m, EPS);
    const float sc = 127.0f / mc;
#pragma unroll
    for (int j = 0; j < 6; ++j) {
        uint32_t p0 = 0, p1 = 0;
#pragma unroll
        for (int i = 0; i < 4; ++i) {
            int c = (int)fminf(rintf(vals[j * 8 + i] * sc), 127.0f);
            p0 |= (uint32_t)(c & 255) << (8 * i);
        }
#pragma unroll
        for (int i = 0; i < 4; ++i) {
            int c = (int)fminf(rintf(vals[j * 8 + 4 + i] * sc), 127.0f);
            p1 |= (uint32_t)(c & 255) << (8 * i);
        }
        uint2 pk; pk.x = p0; pk.y = p1;
        ((uint2*)rp)[j * 64 + lane] = pk;
    }
    if (lane == 0) deq[row] = mc / 127.0f;
}

// ---------------- int8 GEMM: C[m][n] = sum_k A[m][k]*B[n][k] ----------------
// 128(m)x256(n), 256 thr = 4 waves (2x2), wave tile 64x128 as 2x4 of
// v_mfma_i32_32x32x32_i8. RING-2 BK=64 LDS (48 KB) -> 3 blocks/CU
// (__launch_bounds__(256,3)): the third co-resident block supplies the
// cross-block phase offset that fills barrier stalls (R5 pipe accounting:
// MFMA 33% + LDS 44% + VALU 18% serialized; concurrency is the gap, not pipe
// capacity). Schedule per iter: STAGE(tt+1) at top (into the buffer whose
// reads finished last iter), ds_read+MFMA on buf[tt&1], end-drain
// vmcnt(0)+lgkmcnt(0)+barrier. The drain is cheap: tt+1's loads had a full
// iter (~1500 cyc >> 900 cyc HBM) to land. K templated + full unroll: all
// buffer offsets / K-offsets are immediates (zero in-loop VALU, R5-proven).
// LDS rows 64 B; 16 B chunks XOR-swizzled by (row>>1)&3 folded into staging
// lanes' GLOBAL addresses. XCD map: blk&7 (bm-strip stays on one XCD L2).
template <int K, int NTILES, bool RELU2, typename OutT>
__global__ __launch_bounds__(256, 3) void gemm_i8(
    const int8_t* __restrict__ A, int lda,        // row pitch in bytes
    const int8_t* __restrict__ B, int ldb,
    OutT* __restrict__ O, int ldo,                // pitch in elements
    const float* __restrict__ rowDeq,
    const float* __restrict__ sumPtr,
    const float* __restrict__ bias) {
    constexpr int NT = K >> 6;                    // K-tiles of 64
    __shared__ __align__(16) char lds[2][24576];  // per buf: A 8K @0 | B 16K @8192
    const int t = threadIdx.x;
    const int lane = t & 63;
    const int w = t >> 6;                         // wave 0..3
    const int xcd = blockIdx.x & 7;
    const int sb = blockIdx.x >> 3;
    const int bm = xcd + 8 * (sb / NTILES);
    const int bn = sb % NTILES;
    const long m0 = (long)bm * 128;
    const long n0 = (long)bn * 256;

    v16i acc[2][4];
#pragma unroll
    for (int i = 0; i < 2; ++i)
#pragma unroll
        for (int j = 0; j < 4; ++j) acc[i][j] = (v16i)(0);

    const int mloc = (w >> 1) * 64;
    const int nloc = (w & 1) * 128;
    const int r32 = lane & 31;
    const int h = lane >> 5;

    // ---- staging bases (loop-invariant): 6 pointers, K-advance via imm ----
    const int srow = lane >> 2;
    const int scS = ((lane & 3) ^ ((lane >> 3) & 3)) * 16;  // pre-swizzled chunk
    const int8_t* paS0 = A + (m0 + w * 32 + srow) * (long)lda + scS;
    const int8_t* paS1 = paS0 + 16 * (long)lda;
    const int8_t* pbS0 = B + (n0 + w * 64 + srow) * (long)ldb + scS;
    const int8_t* pbS1 = pbS0 + 16 * (long)ldb;
    const int8_t* pbS2 = pbS0 + 32 * (long)ldb;
    const int8_t* pbS3 = pbS0 + 48 * (long)ldb;

    // ---- fragment-read bases (loop-invariant): chunk (2ks+h)^((r>>1)&3) ----
    const int swz = (r32 >> 1) & 3;
    const char* rdA0 = &lds[0][0] + (mloc + r32) * 64 + ((h ^ swz) * 16);
    const char* rdA1 = &lds[0][0] + (mloc + r32) * 64 + (((2 + h) ^ swz) * 16);
    const char* rdB0 = &lds[0][0] + 8192 + (nloc + r32) * 64 + ((h ^ swz) * 16);
    const char* rdB1 = &lds[0][0] + 8192 + (nloc + r32) * 64 + (((2 + h) ^ swz) * 16);

    auto STAGE = [&](int tt) {                    // tt compile-time after unroll
        char* buf = &lds[0][0] + (tt & 1) * 24576;
        const long ko = (long)tt << 6;
        __builtin_amdgcn_global_load_lds((g_void*)(paS0 + ko),
                                         (l_void*)(buf + w * 2048), 16, 0, 0);
        __builtin_amdgcn_global_load_lds((g_void*)(paS1 + ko),
                                         (l_void*)(buf + w * 2048 + 1024), 16, 0, 0);
        __builtin_amdgcn_global_load_lds((g_void*)(pbS0 + ko),
                                         (l_void*)(buf + 8192 + w * 4096), 16, 0, 0);
        __builtin_amdgcn_global_load_lds((g_void*)(pbS1 + ko),
                                         (l_void*)(buf + 8192 + w * 4096 + 1024), 16, 0, 0);
        __builtin_amdgcn_global_load_lds((g_void*)(pbS2 + ko),
                                         (l_void*)(buf + 8192 + w * 4096 + 2048), 16, 0, 0);
        __builtin_amdgcn_global_load_lds((g_void*)(pbS3 + ko),
                                         (l_void*)(buf + 8192 + w * 4096 + 3072), 16, 0, 0);
    };

    // prologue: stage tile 0, drain, publish
    STAGE(0);
    asm volatile("s_waitcnt vmcnt(0)" ::: "memory");
    __builtin_amdgcn_s_barrier();
    __builtin_amdgcn_sched_barrier(0);

#pragma unroll
    for (int tt = 0; tt < NT; ++tt) {
        const int bo = (tt & 1) * 24576;          // compile-time after unroll
        if (tt + 1 < NT) STAGE(tt + 1);           // into the other buffer
        __builtin_amdgcn_sched_barrier(0);        // pin prefetch issue at top
        v4i af[2][2], bf[2][4];                   // [ks][...]
#pragma unroll
        for (int ks = 0; ks < 2; ++ks) {
            const char* rA = ks ? rdA1 : rdA0;
            const char* rB = ks ? rdB1 : rdB0;
#pragma unroll
            for (int mt = 0; mt < 2; ++mt)
                af[ks][mt] = *(const v4i*)(rA + bo + mt * 2048);
#pragma unroll
            for (int nt = 0; nt < 4; ++nt)
                bf[ks][nt] = *(const v4i*)(rB + bo + nt * 2048);
        }
#pragma unroll
        for (int ks = 0; ks < 2; ++ks)
#pragma unroll
            for (int mt = 0; mt < 2; ++mt)
#pragma unroll
                for (int nt = 0; nt < 4; ++nt)
                    acc[mt][nt] = __builtin_amdgcn_mfma_i32_32x32x32_i8(
                        af[ks][mt], bf[ks][nt], acc[mt][nt], 0, 0, 0);
        if (tt + 1 < NT) {
            // drain tile tt+1's loads (issued a full iter ago) and publish
            asm volatile("s_waitcnt vmcnt(0) lgkmcnt(0)" ::: "memory");
            __builtin_amdgcn_s_barrier();
            __builtin_amdgcn_sched_barrier(0);
        }
    }

    // epilogue: C/D layout col = lane&31, row = (reg&3) + 8*(reg>>2) + 4*(lane>>5)
    const float wdeq = fmaxf(sumPtr[0] * (1.0f / 3145728.0f), EPS);
#pragma unroll
    for (int mt = 0; mt < 2; ++mt) {
#pragma unroll
        for (int g = 0; g < 4; ++g) {
#pragma unroll
            for (int rr = 0; rr < 4; ++rr) {
                const long row = m0 + mloc + mt * 32 + g * 8 + h * 4 + rr;
                const float rs = rowDeq[row] * wdeq;
#pragma unroll
                for (int nt = 0; nt < 4; ++nt) {
                    const long col = n0 + nloc + nt * 32 + r32;
                    float val = (float)acc[mt][nt][g * 4 + rr] * rs + bias[col];
                    if (RELU2) {
                        val = fmaxf(val, 0.0f);
                        val = val * val;
                    }
                    O[row * (long)ldo + col] = (OutT)val;
                }
            }
        }
    }
}

// ---------------- launch ----------------
extern "C" void kernel_launch(void* const* d_in, const int* in_sizes, int n_in,
                              void* d_out, int out_size, void* d_ws, size_t ws_size,
                              hipStream_t stream) {
    const float* x      = (const float*)d_in[0];   // [32768,1024]
    const float* up_w   = (const float*)d_in[1];   // [3072,1024]
    const float* up_b   = (const float*)d_in[2];   // [3072]
    const float* down_w = (const float*)d_in[3];   // [1024,3072]
    const float* down_b = (const float*)d_in[4];   // [1024]

    // ws: sums 256B | parts 8KB | qw_dn 3MB | deqh 128KB | hidden bf16 201MB
    char* ws = (char*)d_ws;
    float*  sums   = (float*)ws;
    float*  parts  = (float*)(ws + 256);
    int8_t* qw_dn  = (int8_t*)(ws + 256 + 8192);
    float*  deqh   = (float*)(ws + 256 + 8192 + 3145728);
    __hip_bfloat16* hidden = (__hip_bfloat16*)(ws + 256 + 8192 + 3145728 + 131072);

    // d_out head as phase-1 scratch (dead before GEMM2 writes)
    int8_t* qx    = (int8_t*)d_out;                      // 33.5MB
    int8_t* qw_up = qx + 33554432;                       // 3MB
    float*  deqx  = (float*)(qx + 33554432 + 3145728);   // 128KB

    abs_sum_part_k<<<2048, 256, 0, stream>>>((const float4*)up_w,
                                             (const float4*)down_w, parts);
    abs_sum_final_k<<<2, 256, 0, stream>>>(parts, sums);

    wquant_k<<<6144, 256, 0, stream>>>((const float4*)up_w, (const float4*)down_w,
                                       (char4*)qw_up, (char4*)qw_dn, sums);
    aquant_k<<<8192, 256, 0, stream>>>((const float4*)x, (char4*)qx, deqx);

    // GEMM1: [32768,1024] x [3072,1024]^T -> hidden bf16 (relu^2 fused)
    // grid: 256 m-tiles x 12 n-tiles = 3072 blocks
    gemm_i8<1024, 12, true, __hip_bfloat16><<<3072, 256, 0, stream>>>(
        qx, 1024, qw_up, 1024, hidden, 3072, deqx, &sums[0], up_b);
    // quantize hidden rows in place (int8 overlaid, pitch 6144 B)
    hquant_k<<<8192, 256, 0, stream>>>((unsigned short*)hidden, deqh);
    // GEMM2: [32768,3072] x [1024,3072]^T -> d_out fp32
    // grid: 256 m-tiles x 4 n-tiles = 1024 blocks
    gemm_i8<3072, 4, false, float><<<1024, 256, 0, stream>>>(
        (const int8_t*)hidden, 6144, qw_dn, 3072, (float*)d_out, 1024,
        deqh, &sums[1], down_b);
}